// Round 15
// baseline (786.649 us; speedup 1.0000x reference)
//
#include <hip/hip_runtime.h>
#include <hip/hip_cooperative_groups.h>
#include <math.h>

#define PI_F 3.14159265358979323846f

namespace cg = cooperative_groups;

typedef __bf16 bf16x8 __attribute__((ext_vector_type(8)));
typedef float floatx4 __attribute__((ext_vector_type(4)));
union U8 { unsigned short u[8]; uint4 q; bf16x8 v; };

// sigmoid-form GELU: v * sigmoid(1.702 v)
__device__ __forceinline__ float gelu_sig(float v) {
    float e = __builtin_amdgcn_exp2f(-2.4554670f * v);   // exp(-1.702 v)
    return v * __builtin_amdgcn_rcpf(1.0f + e);
}
__device__ __forceinline__ int rfl(int x) { return __builtin_amdgcn_readfirstlane(x); }

__device__ __forceinline__ unsigned short f2bf(float f) {   // RNE fp32->bf16
    unsigned int u = __float_as_uint(f);
    u += 0x7fffu + ((u >> 16) & 1u);
    return (unsigned short)(u >> 16);
}
__device__ __forceinline__ float bf2f(unsigned short h) {
    return __uint_as_float(((unsigned int)h) << 16);
}
__device__ __forceinline__ unsigned int pack2(float a, float b) {
    return (unsigned int)f2bf(a) | ((unsigned int)f2bf(b) << 16);
}

// -------- k_wt: k_emb (blocks 0-1) + bf16 constants + twiddles (blocks 2-39)
//          + spec-weight transpose wT[l][mode(kz,ky,kx)][i][o] f2 (blocks 40-551) --------
__global__ void k_wt(const float* __restrict__ time_i, const float* __restrict__ conditions,
                     const float* __restrict__ t_embed_w, const float* __restrict__ t_embed_b,
                     const float* __restrict__ c_embed_w, const float* __restrict__ c_embed_b,
                     const float* __restrict__ lift_b, float* __restrict__ embk,
                     const float* __restrict__ byp_w, const float* __restrict__ lift_w,
                     unsigned short* __restrict__ wbh, unsigned short* __restrict__ wlbf,
                     unsigned short* __restrict__ Tinv, unsigned short* __restrict__ TfT,
                     float* __restrict__ Tp1g, const float* __restrict__ spec_wr,
                     const float* __restrict__ spec_wi, float2* __restrict__ wT) {
    const float th = PI_F / 32.0f;
    __shared__ float red[8][32];
    __shared__ __align__(16) float2 TT[4160];   // [o8][520] padded
    int t = threadIdx.x;
    if (blockIdx.x < 2) {   // embedding
        int b = blockIdx.x;
        int c = t & 31, lg = t >> 5;
        float acc = 0.0f;
        if (lg == 0) {
            acc = t_embed_b[c] + c_embed_b[c] + lift_b[c];
            float tv = time_i[b];
            float ang = PI_F * tv;
            const float* tw = t_embed_w + c * 11;
            for (int i = 0; i < 5; i++) {
                float s, co; sincosf(ang, &s, &co);
                acc += co * tw[i] + s * tw[5 + i];
                ang *= 2.0f;
            }
            acc += tv * tw[10];
        }
        const float* cw = c_embed_w + c * 352;
        for (int j = 0; j < 4; j++) {
            int l = lg * 4 + j;
            float v = conditions[b * 32 + l];
            float ang = PI_F * v;
            for (int i = 0; i < 5; i++) {
                float s, co; sincosf(ang, &s, &co);
                acc += co * cw[l * 10 + i] + s * cw[l * 10 + 5 + i];
                ang *= 2.0f;
            }
            acc += v * cw[320 + l];
        }
        red[lg][c] = acc;
        __syncthreads();
        if (t < 32) {
            float s = 0.0f;
            for (int g = 0; g < 8; g++) s += red[g][t];
            embk[b * 32 + t] = s;
        }
        return;
    }
    if (blockIdx.x >= 40) {   // spec-weight transpose: block = (l, i, og)
        int n = blockIdx.x - 40;
        int l = n >> 7, i = (n & 127) >> 2, og = n & 3;
        size_t srcb = ((size_t)(l * 1024 + i * 32 + og * 8)) * 512;
        for (int k = 0; k < 16; k++) {
            int e = k * 256 + t;              // o8 = e>>9, m = e&511
            TT[(e >> 9) * 520 + (e & 511)] =
                make_float2(spec_wr[srcb + e], spec_wi[srcb + e]);
        }
        __syncthreads();
        for (int k = 0; k < 16; k++) {
            int e = k * 256 + t;              // o = e&7, mo = e>>3
            int o = e & 7, mo = e >> 3;
            int sm = ((mo & 7) << 6) | (mo & 56) | (mo >> 6);   // swap kx<->kz
            wT[(size_t)l * 524288 + (size_t)mo * 1024 + i * 32 + og * 8 + o]
                = TT[o * 520 + sm];
        }
        return;
    }
    int idx = (blockIdx.x - 2) * 256 + t;
    if (idx < 4096) {
        wbh[idx] = f2bf(byp_w[idx]);          // [l][o][i] (A-fragment layout)
    } else if (idx < 6144) {
        int j = idx - 4096;                   // o*64 + q
        int o = j >> 6, q = j & 63;
        wlbf[j] = (q < 37) ? f2bf(lift_w[o * 37 + q]) : 0;
    } else if (idx < 8192) {
        int j = idx - 6144;                   // nz*32 + k
        int nz = j >> 5, k = j & 31;
        int kz = k >> 1;
        float val = 0.0f;
        if (kz < 8) {
            float a = (float)((kz * nz) & 63) * th;
            val = (k & 1) ? sinf(a) : cosf(a);
            val *= (kz == 0) ? (1.0f / 262144.0f) : (2.0f / 262144.0f);   // fold scale
        }
        Tinv[j] = f2bf(val);
    } else if (idx < 9216) {
        int j = idx - 8192;                   // kcol*64 + nz
        int kcol = j >> 6, nz = j & 63;
        int kz = kcol >> 1;
        float a = (float)((kz * nz) & 63) * th;
        float val = (kcol & 1) ? -sinf(a) : cosf(a);
        TfT[j] = f2bf(val);
    } else if (idx < 9728) {
        int j = idx - 9216;                   // ny*8 + ky
        int ny = j >> 3, ky = j & 7;
        float a = (float)((ky * ny) & 63) * th;
        Tp1g[j * 2] = cosf(a);
        Tp1g[j * 2 + 1] = sinf(a);
    }
}

// XCD swizzle for 8192-block grids
__device__ __forceinline__ void swz8k(int blk, int& b, int& nx, int& ny) {
    int x = blk & 7;
    int j = blk >> 3;
    int pair = x * 16 + (j >> 6);
    ny = j & 63;
    b = pair >> 6;
    nx = pair & 63;
}

// x tile layout: [b][nxy][nz][pos] bf16, pos = quad*8 + ot*4 + r  <->  c = ot*16 + quad*4 + r.
// Writer emits one uint4/lane (fully coalesced); reader takes two uint2/lane (covered lines).

// ------- k_lift: MFMA lift conv + emb + MFMA forward z-DFT. -------
__global__ __launch_bounds__(256) void k_lift(const float* __restrict__ state_in,
        const float* __restrict__ node_pos, const unsigned short* __restrict__ wlbf,
        const float* __restrict__ embk, const unsigned short* __restrict__ TfT,
        unsigned short* __restrict__ x0, unsigned int* __restrict__ a1) {
    __shared__ __align__(16) float SL[3456];
    unsigned short* fsT  = (unsigned short*)SL;          // [nz][72] u16 (2304 f)
    unsigned short* ysbf = (unsigned short*)(SL + 2304); // [o][72] u16 (1152 f)
    int t = threadIdx.x;
    int b, nx, ny; swz8k(blockIdx.x, b, nx, ny);
    int nxy = nx * 64 + ny;

    {
        for (int u = t; u < 2048; u += 256) {
            int row = u >> 5, col = 37 + (u & 31);
            fsT[row * 72 + col] = 0;
        }
    }
    if (t < 192) {
        int nzf = t / 3;
        int l = t - nzf * 3;
        float p = node_pos[((size_t)b * 262144 + (nxy << 6)) * 3 + t];
        float s, c; sincosf(PI_F * p, &s, &c);
        unsigned short* row = fsT + nzf * 72;
        #pragma unroll
        for (int i = 0; i < 5; i++) {
            row[4 + l * 10 + i] = f2bf(c);
            row[4 + l * 10 + 5 + i] = f2bf(s);
            float nc = 2.0f * c * c - 1.0f;
            s = 2.0f * s * c;
            c = nc;
        }
        row[34 + l] = f2bf(p);
    } else {
        int nzf = t - 192;
        const float4 s4 = *(const float4*)(state_in + ((size_t)b * 262144 + (nxy << 6) + nzf) * 4);
        unsigned short* row = fsT + nzf * 72;
        row[0] = f2bf(s4.x); row[1] = f2bf(s4.y);
        row[2] = f2bf(s4.z); row[3] = f2bf(s4.w);
    }
    __syncthreads();

    int lane = t & 63;
    int w = rfl(t >> 6);
    int l15 = lane & 15;
    int quad = lane >> 4;
    int nz = w * 16 + l15;
    size_t xbase = ((size_t)(b * 4096 + nxy)) * 2048;

    U8 b0, b1_;
    b0.q  = *(const uint4*)(fsT + nz * 72 + (quad << 3));
    b1_.q = *(const uint4*)(fsT + nz * 72 + 32 + (quad << 3));
    unsigned short hh[2][4];
    #pragma unroll
    for (int ot = 0; ot < 2; ot++) {
        U8 aA, aB;
        aA.q = *(const uint4*)(wlbf + ((ot * 16 + l15) << 6) + (quad << 3));
        aB.q = *(const uint4*)(wlbf + ((ot * 16 + l15) << 6) + 32 + (quad << 3));
        float4 cbv = *(const float4*)(embk + b * 32 + ot * 16 + quad * 4);  // L1 broadcast
        floatx4 cb = {cbv.x, cbv.y, cbv.z, cbv.w};
        floatx4 d = __builtin_amdgcn_mfma_f32_16x16x32_bf16(aA.v, b0.v, cb, 0, 0, 0);
        d = __builtin_amdgcn_mfma_f32_16x16x32_bf16(aB.v, b1_.v, d, 0, 0, 0);
        #pragma unroll
        for (int r = 0; r < 4; r++) {
            hh[ot][r] = f2bf(d[r]);
            ysbf[(ot * 16 + quad * 4 + r) * 72 + nz] = hh[ot][r];
        }
    }
    *(uint4*)(x0 + xbase + nz * 32 + (quad << 3)) = make_uint4(
        (unsigned)hh[0][0] | ((unsigned)hh[0][1] << 16),
        (unsigned)hh[0][2] | ((unsigned)hh[0][3] << 16),
        (unsigned)hh[1][0] | ((unsigned)hh[1][1] << 16),
        (unsigned)hh[1][2] | ((unsigned)hh[1][3] << 16));
    __syncthreads();

    if (w < 2) {   // forward z-DFT: chained K, one wave per o-tile
        int o = w * 16 + l15;
        U8 ay0, ay1, bt0, bt1;
        ay0.q = *(const uint4*)(ysbf + o * 72 + (quad << 3));
        ay1.q = *(const uint4*)(ysbf + o * 72 + 32 + (quad << 3));
        bt0.q = *(const uint4*)(TfT + (l15 << 6) + (quad << 3));
        bt1.q = *(const uint4*)(TfT + (l15 << 6) + 32 + (quad << 3));
        floatx4 z = {0.0f, 0.0f, 0.0f, 0.0f};
        z = __builtin_amdgcn_mfma_f32_16x16x32_bf16(ay0.v, bt0.v, z, 0, 0, 0);
        z = __builtin_amdgcn_mfma_f32_16x16x32_bf16(ay1.v, bt1.v, z, 0, 0, 0);
        float p0 = __shfl_xor(z[0], 1), p1 = __shfl_xor(z[1], 1);
        float p2 = __shfl_xor(z[2], 1), p3 = __shfl_xor(z[3], 1);
        if (!(lane & 1)) {
            unsigned int* a1p = a1 + ((size_t)(b * 4096 + nxy)) * 256;
            int kz = l15 >> 1;
            a1p[(w * 16 + quad * 4 + 0) * 8 + kz] = pack2(z[0], p0);
            a1p[(w * 16 + quad * 4 + 1) * 8 + kz] = pack2(z[1], p1);
            a1p[(w * 16 + quad * 4 + 2) * 8 + kz] = pack2(z[2], p2);
            a1p[(w * 16 + quad * 4 + 3) * 8 + kz] = pack2(z[3], p3);
        }
    }
}

// =================== spectral mid-section (1 cooperative kernel) ===================

// k_ps12: ps1 (512 blocks) -> grid.sync -> ps2 (blocks 0-127). Identical bodies,
// kernel-boundary replaced by grid barrier (saves 4 launches + 4 full drains).
__global__ __launch_bounds__(256) void k_ps12(const unsigned int* __restrict__ a1,
        const float2* __restrict__ wTl, const float2* __restrict__ Tp1g,
        float2* __restrict__ a2p, float2* __restrict__ b1) {
    __shared__ __align__(16) float2 MS[2048];   // [nx][c]
    __shared__ __align__(16) float2 TW[512];    // [n][k] twiddle (cos,sin of nkθ)
    __shared__ __align__(16) float2 XS[256];    // [i][kx]
    __shared__ __align__(16) float2 YS[288];    // [o][9] padded
    cg::grid_group grid = cg::this_grid();
    int t = threadIdx.x, blk = blockIdx.x;

    {   // ---- phase 1: forward y-DFT over ny-QUARTERS (all 512 blocks) ----
        int x = blk & 7, r = blk >> 3;
        int pair = x * 16 + (r & 15);         // b*64+nx
        int qtr = r >> 4;
        const unsigned int* src = a1 + ((size_t)(pair * 64 + qtr * 16)) * 256 + t;
        float accr[8], acci[8];
        #pragma unroll
        for (int k = 0; k < 8; k++) { accr[k] = 0.0f; acci[k] = 0.0f; }
        #pragma unroll 4
        for (int j = 0; j < 16; j++) {
            int ny = qtr * 16 + j;
            unsigned int pv = src[(size_t)j * 256];
            float vx = bf2f((unsigned short)(pv & 0xffffu));
            float vy = bf2f((unsigned short)(pv >> 16));
            const float2* tw = Tp1g + ny * 8;    // block-uniform -> s_load
            #pragma unroll
            for (int ky = 0; ky < 8; ky++) {
                float2 w2 = tw[ky];
                accr[ky] += vx * w2.x + vy * w2.y;   // e^{-i ky ny θ}
                acci[ky] += vy * w2.x - vx * w2.y;
            }
        }
        int b = pair >> 6, nx = pair & 63;
        int c = t >> 3, kz = t & 7;
        float2* dst = a2p + ((size_t)((qtr * 2 + b) * 8 + kz)) * 16384 + nx * 32 + c;
        #pragma unroll
        for (int ky = 0; ky < 8; ky++)
            dst[(size_t)ky * 2048] = make_float2(accr[ky], acci[ky]);
    }
    __threadfence();
    grid.sync();
    if (blk >= 128) return;

    // ---- phase 2: quarter-sum + x-DFT + mode-mix + inverse-x (blocks 0-127) ----
    int b = blk >> 6, kz = (blk >> 3) & 7, ky = blk & 7;
    size_t sb = (size_t)b * 131072 + kz * 16384 + ky * 2048;
    for (int k = 0; k < 8; k++) {               // A: quarter-sum
        int e = k * 256 + t;
        float2 v0 = a2p[sb + e];
        float2 v1 = a2p[sb + 262144 + e];
        float2 v2 = a2p[sb + 524288 + e];
        float2 v3 = a2p[sb + 786432 + e];
        MS[e] = make_float2(v0.x + v1.x + v2.x + v3.x,
                            v0.y + v1.y + v2.y + v3.y);
    }
    TW[t] = Tp1g[t];
    TW[256 + t] = Tp1g[256 + t];
    __syncthreads();
    {   // B: x-DFT via table, thread (c = t>>3, kx = t&7); independent iters (ILP)
        int c = t >> 3, kx = t & 7;
        float xr = 0.0f, xi = 0.0f;
        #pragma unroll 8
        for (int nx = 0; nx < 64; nx++) {
            float2 v = MS[nx * 32 + c];
            float2 w2 = TW[nx * 8 + kx];
            xr += v.x * w2.x + v.y * w2.y;       // e^{-i kx nx θ}
            xi += v.y * w2.x - v.x * w2.y;
        }
        XS[c * 8 + kx] = make_float2(xr, xi);
    }
    __syncthreads();
    {   // C: mode mix, thread (kx = t>>5, o = t&31); wT coalesced o-inner
        int kx = t >> 5, o = t & 31;
        const float2* wp = wTl + ((size_t)(kz * 64 + ky * 8 + kx)) * 1024 + o;
        float yr = 0.0f, yi = 0.0f;
        #pragma unroll 8
        for (int i = 0; i < 32; i++) {
            float2 xv = XS[i * 8 + kx];
            float2 wv = wp[i * 32];
            yr += xv.x * wv.x - xv.y * wv.y;
            yi += xv.x * wv.y + xv.y * wv.x;
        }
        YS[o * 9 + kx] = make_float2(yr, yi);
    }
    __syncthreads();
    {   // D: inverse-x (e^{+i}) via table, thread (nx8 = t>>5, o = t&31)
        int nx8 = t >> 5, o = t & 31;
        for (int j = 0; j < 8; j++) {
            int nx = nx8 * 8 + j;
            float rr = 0.0f, ri = 0.0f;
            #pragma unroll
            for (int kx = 0; kx < 8; kx++) {
                float2 y = YS[o * 9 + kx];
                float2 w2 = TW[nx * 8 + kx];
                rr += y.x * w2.x - y.y * w2.y;
                ri += y.x * w2.y + y.y * w2.x;
            }
            b1[((size_t)(b * 64 + nx)) * 2048 + (kz * 8 + ky) * 32 + o]
                = make_float2(rr, ri);
        }
    }
}

// ------- k_fin: LDS-staged b1 tile + register inverse-y + chained MFMA + gelu.
//         LDS phase-aliased: ysbf/pr overlay the dead bstage region after the
//         inverse-y barrier -> 17.9 KB total, 9 blocks/CU.
//         + (l<3) chained-K MFMA fwd z-DFT OR (l==3) fused proj+residual -------
__global__ __launch_bounds__(256) void k_fin(
        const unsigned short* __restrict__ xin, const float2* __restrict__ b1,
        const unsigned short* __restrict__ wbh, const float* __restrict__ bb,
        const unsigned short* __restrict__ Tinv, const unsigned short* __restrict__ TfT,
        const float2* __restrict__ Tp1g, unsigned short* __restrict__ xout,
        unsigned int* __restrict__ a1, int do_z, int do_proj,
        const float* __restrict__ state_in, const float* __restrict__ p1w,
        const float* __restrict__ p1b, const float* __restrict__ p2w,
        const float* __restrict__ p2b, float* __restrict__ outp) {
    __shared__ __align__(16) float S[4480];
    float* bstage = S;                                    // f 0..4220 (phases 1-2 only)
    unsigned short* ysbf = (unsigned short*)S;            // [o][72] u16, f 0..1152 (phase 3+)
    float* pr = S + 1152;                                 // f 1152..2176 (proj, phase 4+)
    unsigned int* msu = (unsigned int*)(S + 4224);        // [32 o][8 kz] uint, f 4224..4480
    int t = threadIdx.x;
    int b, nx, ny; swz8k(blockIdx.x, b, nx, ny);
    int nxy = nx * 64 + ny;
    int lane = t & 63;
    int w = rfl(t >> 6);
    int l15 = lane & 15;
    int quad = lane >> 4;
    int nz = w * 16 + l15;
    size_t xbase = ((size_t)(b * 4096 + nxy)) * 2048;

    // early fragment loads: latency hides under staging + inverse-y
    int posA = ((quad & 1) << 4) | ((quad >> 1) << 2);
    uint2 xlo = *(const uint2*)(xin + xbase + nz * 32 + posA);
    uint2 xhi = *(const uint2*)(xin + xbase + nz * 32 + posA + 8);
    U8 bx, btv, aw0, aw1;
    ((uint2*)&bx)[0] = xlo; ((uint2*)&bx)[1] = xhi;
    btv.q = *(const uint4*)(Tinv + (nz << 5) + (quad << 3));        // L1-broadcast
    aw0.q = *(const uint4*)(wbh + (l15 << 5) + (quad << 3));
    aw1.q = *(const uint4*)(wbh + ((16 + l15) << 5) + (quad << 3));
    float4 c0 = *(const float4*)(bb + quad * 4);                    // L1-broadcast bias
    float4 c1 = *(const float4*)(bb + 16 + quad * 4);
    floatx4 cb0 = {c0.x, c0.y, c0.z, c0.w};
    floatx4 cb1 = {c1.x, c1.y, c1.z, c1.w};

    // phase 1: stage b1 tile (16 KB) -> LDS, fully lane-coalesced (1 KB/instr/wave).
    // LDS pad: f2-slot s lives at byte s*8 + (s>>6)*16 (floor bank cost both sides).
    {
        const float4* b1g = (const float4*)(b1 + ((size_t)(b * 64 + nx)) * 2048);
        #pragma unroll
        for (int j = 0; j < 4; j++) {
            int p = j * 256 + t;              // f2-pair index, covers 0..1023
            float4 v = b1g[p];
            int s = p * 2;
            *(float4*)((char*)bstage + s * 8 + ((s >> 6) << 4)) = v;
        }
    }
    __syncthreads();

    {   // phase 2: inverse-y from staged LDS; thread (o = t>>3, kz = t&7); writes msu
        int o_ = t >> 3, kz_ = t & 7;
        const float2* tw = Tp1g + ny * 8;          // block-uniform -> s_load
        float mr = 0.0f, mi = 0.0f;
        #pragma unroll
        for (int ky = 0; ky < 8; ky++) {
            int g = kz_ * 256 + ky * 32 + o_;
            float2 v = *(const float2*)((char*)bstage + g * 8 + ((g >> 6) << 4));
            float2 w2 = tw[ky];
            mr += v.x * w2.x - v.y * w2.y;         // e^{+i ky ny θ}
            mi += v.x * w2.y + v.y * w2.x;
        }
        msu[o_ * 8 + kz_] = pack2(mr, -mi);
    }
    __syncthreads();   // bstage dead from here; ysbf/pr may overlay it

    // ---- phase 3: chained MFMA, both o-tiles in one wave (wave = nz-tile):
    //      D = bias + W·X (bypass) + M·Tinv (inverse-z, scale folded in Tinv) ----
    U8 am0, am1;
    if (quad < 2) {   // M fragment: K-cols 0..15 real, 16..31 zero (Tinv rows 8..15 = 0 too)
        am0.q = *(const uint4*)(msu + l15 * 8 + quad * 4);
        am1.q = *(const uint4*)(msu + (16 + l15) * 8 + quad * 4);
    } else {
        am0.q = make_uint4(0, 0, 0, 0);
        am1.q = make_uint4(0, 0, 0, 0);
    }
    floatx4 d0 = __builtin_amdgcn_mfma_f32_16x16x32_bf16(aw0.v, bx.v, cb0, 0, 0, 0);
    d0 = __builtin_amdgcn_mfma_f32_16x16x32_bf16(am0.v, btv.v, d0, 0, 0, 0);
    floatx4 d1 = __builtin_amdgcn_mfma_f32_16x16x32_bf16(aw1.v, bx.v, cb1, 0, 0, 0);
    d1 = __builtin_amdgcn_mfma_f32_16x16x32_bf16(am1.v, btv.v, d1, 0, 0, 0);

    unsigned short h0[4], h1[4];
    #pragma unroll
    for (int r = 0; r < 4; r++) {
        h0[r] = f2bf(gelu_sig(d0[r]));
        ysbf[(quad * 4 + r) * 72 + nz] = h0[r];
        h1[r] = f2bf(gelu_sig(d1[r]));
        ysbf[(16 + quad * 4 + r) * 72 + nz] = h1[r];
    }
    if (!do_proj) {   // one clean uint4/lane: wave covers 1 KB contiguous
        *(uint4*)(xout + xbase + nz * 32 + (quad << 3)) = make_uint4(
            (unsigned)h0[0] | ((unsigned)h0[1] << 16),
            (unsigned)h0[2] | ((unsigned)h0[3] << 16),
            (unsigned)h1[0] | ((unsigned)h1[1] << 16),
            (unsigned)h1[2] | ((unsigned)h1[3] << 16));
    }
    __syncthreads();

    if (do_z && w < 2) {   // phase 4a: forward z-DFT, chained K, one wave per o-tile
        int o = w * 16 + l15;
        U8 ay0, ay1, bt0, bt1;
        ay0.q = *(const uint4*)(ysbf + o * 72 + (quad << 3));
        ay1.q = *(const uint4*)(ysbf + o * 72 + 32 + (quad << 3));
        bt0.q = *(const uint4*)(TfT + (l15 << 6) + (quad << 3));
        bt1.q = *(const uint4*)(TfT + (l15 << 6) + 32 + (quad << 3));
        floatx4 z = {0.0f, 0.0f, 0.0f, 0.0f};
        z = __builtin_amdgcn_mfma_f32_16x16x32_bf16(ay0.v, bt0.v, z, 0, 0, 0);
        z = __builtin_amdgcn_mfma_f32_16x16x32_bf16(ay1.v, bt1.v, z, 0, 0, 0);
        float p0 = __shfl_xor(z[0], 1), p1 = __shfl_xor(z[1], 1);
        float p2 = __shfl_xor(z[2], 1), p3 = __shfl_xor(z[3], 1);
        if (!(lane & 1)) {
            unsigned int* a1p = a1 + ((size_t)(b * 4096 + nxy)) * 256;
            int kz = l15 >> 1;
            a1p[(w * 16 + quad * 4 + 0) * 8 + kz] = pack2(z[0], p0);
            a1p[(w * 16 + quad * 4 + 1) * 8 + kz] = pack2(z[1], p1);
            a1p[(w * 16 + quad * 4 + 2) * 8 + kz] = pack2(z[2], p2);
            a1p[(w * 16 + quad * 4 + 3) * 8 + kz] = pack2(z[3], p3);
        }
    }

    if (do_proj) {   // phase 4b: fused proj1 -> gelu -> proj2 -> residual
        int nzp = t & 63;
        float xv[32];
        #pragma unroll
        for (int i = 0; i < 32; i++) xv[i] = bf2f(ysbf[i * 72 + nzp]);
        float r0 = 0.f, r1 = 0.f, r2 = 0.f, r3 = 0.f;
        #pragma unroll
        for (int k = 0; k < 8; k++) {
            int o = w * 8 + k;
            float a = p1b[o];                                   // s_load
            const float* wr = p1w + o * 32;                     // s_load
            #pragma unroll
            for (int i = 0; i < 32; i++) a += wr[i] * xv[i];
            float h = gelu_sig(a);
            r0 += p2w[0 * 32 + o] * h;
            r1 += p2w[1 * 32 + o] * h;
            r2 += p2w[2 * 32 + o] * h;
            r3 += p2w[3 * 32 + o] * h;
        }
        *(float4*)(pr + w * 256 + nzp * 4) = make_float4(r0, r1, r2, r3);
        __syncthreads();
        if (t < 64) {
            float4 a0 = *(float4*)(pr + 0 * 256 + t * 4);
            float4 a1_ = *(float4*)(pr + 1 * 256 + t * 4);
            float4 a2 = *(float4*)(pr + 2 * 256 + t * 4);
            float4 a3 = *(float4*)(pr + 3 * 256 + t * 4);
            size_t base = ((size_t)b * 262144 + (nxy << 6) + t) * 4;
            float4 sv = *(const float4*)(state_in + base);
            *(float4*)(outp + base) = make_float4(
                sv.x + 0.05f * (p2b[0] + a0.x + a1_.x + a2.x + a3.x),
                sv.y + 0.05f * (p2b[1] + a0.y + a1_.y + a2.y + a3.y),
                sv.z + 0.05f * (p2b[2] + a0.z + a1_.z + a2.z + a3.z),
                sv.w + 0.05f * (p2b[3] + a0.w + a1_.w + a2.w + a3.w));
        }
    }
}

extern "C" void kernel_launch(void* const* d_in, const int* in_sizes, int n_in,
                              void* d_out, int out_size, void* d_ws, size_t ws_size,
                              hipStream_t stream) {
    const float* state_in   = (const float*)d_in[0];
    const float* node_pos   = (const float*)d_in[1];
    const float* time_i     = (const float*)d_in[3];
    const float* conditions = (const float*)d_in[4];
    const float* t_embed_w  = (const float*)d_in[5];
    const float* t_embed_b  = (const float*)d_in[6];
    const float* c_embed_w  = (const float*)d_in[7];
    const float* c_embed_b  = (const float*)d_in[8];
    const float* lift_w     = (const float*)d_in[9];
    const float* lift_b     = (const float*)d_in[10];
    const float* spec_wr    = (const float*)d_in[11];
    const float* spec_wi    = (const float*)d_in[12];
    const float* byp_w      = (const float*)d_in[13];
    const float* byp_b      = (const float*)d_in[14];
    const float* proj1_w    = (const float*)d_in[15];
    const float* proj1_b    = (const float*)d_in[16];
    const float* proj2_w    = (const float*)d_in[17];
    const float* proj2_b    = (const float*)d_in[18];
    float* out = (float*)d_out;
    float* ws  = (float*)d_ws;

    unsigned short* xA = (unsigned short*)ws;                 // 16777216 u16
    unsigned short* xB = (unsigned short*)(ws + 8388608);     // 16777216 u16
    unsigned int* a1 = (unsigned int*)(ws + 16777216);        // 1048576 uint (bf16x2)
    float2* a2p  = (float2*)(ws + 20971520);   // 1048576 f2 -> 23068672
    float2* b1   = (float2*)(ws + 23396352);   // 262144 f2  -> 23920640
    float*  embk = ws + 23920640;              // 64
    unsigned short* wbh  = (unsigned short*)(ws + 23920704);  // 4096 u16 -> 23922752
    unsigned short* wlbf = (unsigned short*)(ws + 23922752);  // 2048 u16 -> 23923776
    unsigned short* Tinv = (unsigned short*)(ws + 23923776);  // 2048 u16 -> 23924800
    unsigned short* TfT  = (unsigned short*)(ws + 23924800);  // 1024 u16 -> 23925312
    float* Tp1gf = ws + 23925312;              // 1024 f (512 float2)
    float2* Tp1g = (float2*)Tp1gf;
    float2* wT   = (float2*)(ws + 23926336);   // 2097152 f2 (16 MB) -> 28120640

    k_wt<<<552, 256, 0, stream>>>(time_i, conditions, t_embed_w, t_embed_b,
                                  c_embed_w, c_embed_b, lift_b, embk,
                                  byp_w, lift_w, wbh, wlbf, Tinv, TfT, Tp1gf,
                                  spec_wr, spec_wi, wT);
    k_lift<<<8192, 256, 0, stream>>>(state_in, node_pos, wlbf, embk, TfT, xA, a1);

    for (int l = 0; l < 4; l++) {
        unsigned short* xin  = (l & 1) ? xB : xA;
        unsigned short* xout = (l & 1) ? xA : xB;
        const unsigned int* a1c = a1;
        const float2* wTl = wT + (size_t)l * 524288;
        const float2* Tp1gc = Tp1g;
        float2* a2pc = a2p;
        float2* b1c = b1;
        void* args[5] = {&a1c, &wTl, &Tp1gc, &a2pc, &b1c};
        hipLaunchCooperativeKernel((const void*)k_ps12, dim3(512), dim3(256),
                                   args, 0, stream);
        k_fin<<<8192, 256, 0, stream>>>(xin, b1, wbh + l * 1024, byp_b + l * 32,
                                        Tinv, TfT, Tp1g, xout, a1, (l < 3) ? 1 : 0,
                                        (l == 3) ? 1 : 0, state_in,
                                        proj1_w, proj1_b, proj2_w, proj2_b, out);
    }
}

// Round 16
// 305.773 us; speedup vs baseline: 2.5727x; 2.5727x over previous
//
#include <hip/hip_runtime.h>
#include <math.h>

#define PI_F 3.14159265358979323846f

typedef __bf16 bf16x8 __attribute__((ext_vector_type(8)));
typedef float floatx4 __attribute__((ext_vector_type(4)));
union U8 { unsigned short u[8]; uint4 q; bf16x8 v; };

// sigmoid-form GELU: v * sigmoid(1.702 v)
__device__ __forceinline__ float gelu_sig(float v) {
    float e = __builtin_amdgcn_exp2f(-2.4554670f * v);   // exp(-1.702 v)
    return v * __builtin_amdgcn_rcpf(1.0f + e);
}
__device__ __forceinline__ int rfl(int x) { return __builtin_amdgcn_readfirstlane(x); }

__device__ __forceinline__ unsigned short f2bf(float f) {   // RNE fp32->bf16
    unsigned int u = __float_as_uint(f);
    u += 0x7fffu + ((u >> 16) & 1u);
    return (unsigned short)(u >> 16);
}
__device__ __forceinline__ float bf2f(unsigned short h) {
    return __uint_as_float(((unsigned int)h) << 16);
}
__device__ __forceinline__ unsigned int pack2(float a, float b) {
    return (unsigned int)f2bf(a) | ((unsigned int)f2bf(b) << 16);
}

// -------- k_wt: k_emb (blocks 0-1) + bf16 constants + twiddles (blocks 2-39)
//          + spec-weight transpose wT[l][mode(kz,ky,kx)][i][o] f2 (blocks 40-551) --------
__global__ void k_wt(const float* __restrict__ time_i, const float* __restrict__ conditions,
                     const float* __restrict__ t_embed_w, const float* __restrict__ t_embed_b,
                     const float* __restrict__ c_embed_w, const float* __restrict__ c_embed_b,
                     const float* __restrict__ lift_b, float* __restrict__ embk,
                     const float* __restrict__ byp_w, const float* __restrict__ lift_w,
                     unsigned short* __restrict__ wbh, unsigned short* __restrict__ wlbf,
                     unsigned short* __restrict__ Tinv, unsigned short* __restrict__ TfT,
                     float* __restrict__ Tp1g, const float* __restrict__ spec_wr,
                     const float* __restrict__ spec_wi, float2* __restrict__ wT) {
    const float th = PI_F / 32.0f;
    __shared__ float red[8][32];
    __shared__ __align__(16) float2 TT[4160];   // [o8][520] padded
    int t = threadIdx.x;
    if (blockIdx.x < 2) {   // embedding
        int b = blockIdx.x;
        int c = t & 31, lg = t >> 5;
        float acc = 0.0f;
        if (lg == 0) {
            acc = t_embed_b[c] + c_embed_b[c] + lift_b[c];
            float tv = time_i[b];
            float ang = PI_F * tv;
            const float* tw = t_embed_w + c * 11;
            for (int i = 0; i < 5; i++) {
                float s, co; sincosf(ang, &s, &co);
                acc += co * tw[i] + s * tw[5 + i];
                ang *= 2.0f;
            }
            acc += tv * tw[10];
        }
        const float* cw = c_embed_w + c * 352;
        for (int j = 0; j < 4; j++) {
            int l = lg * 4 + j;
            float v = conditions[b * 32 + l];
            float ang = PI_F * v;
            for (int i = 0; i < 5; i++) {
                float s, co; sincosf(ang, &s, &co);
                acc += co * cw[l * 10 + i] + s * cw[l * 10 + 5 + i];
                ang *= 2.0f;
            }
            acc += v * cw[320 + l];
        }
        red[lg][c] = acc;
        __syncthreads();
        if (t < 32) {
            float s = 0.0f;
            for (int g = 0; g < 8; g++) s += red[g][t];
            embk[b * 32 + t] = s;
        }
        return;
    }
    if (blockIdx.x >= 40) {   // spec-weight transpose: block = (l, i, og)
        int n = blockIdx.x - 40;
        int l = n >> 7, i = (n & 127) >> 2, og = n & 3;
        size_t srcb = ((size_t)(l * 1024 + i * 32 + og * 8)) * 512;
        for (int k = 0; k < 16; k++) {
            int e = k * 256 + t;              // o8 = e>>9, m = e&511
            TT[(e >> 9) * 520 + (e & 511)] =
                make_float2(spec_wr[srcb + e], spec_wi[srcb + e]);
        }
        __syncthreads();
        for (int k = 0; k < 16; k++) {
            int e = k * 256 + t;              // o = e&7, mo = e>>3
            int o = e & 7, mo = e >> 3;
            int sm = ((mo & 7) << 6) | (mo & 56) | (mo >> 6);   // swap kx<->kz
            wT[(size_t)l * 524288 + (size_t)mo * 1024 + i * 32 + og * 8 + o]
                = TT[o * 520 + sm];
        }
        return;
    }
    int idx = (blockIdx.x - 2) * 256 + t;
    if (idx < 4096) {
        wbh[idx] = f2bf(byp_w[idx]);          // [l][o][i] (A-fragment layout)
    } else if (idx < 6144) {
        int j = idx - 4096;                   // o*64 + q
        int o = j >> 6, q = j & 63;
        wlbf[j] = (q < 37) ? f2bf(lift_w[o * 37 + q]) : 0;
    } else if (idx < 8192) {
        int j = idx - 6144;                   // nz*32 + k
        int nz = j >> 5, k = j & 31;
        int kz = k >> 1;
        float val = 0.0f;
        if (kz < 8) {
            float a = (float)((kz * nz) & 63) * th;
            val = (k & 1) ? sinf(a) : cosf(a);
            val *= (kz == 0) ? (1.0f / 262144.0f) : (2.0f / 262144.0f);   // fold scale
        }
        Tinv[j] = f2bf(val);
    } else if (idx < 9216) {
        int j = idx - 8192;                   // kcol*64 + nz
        int kcol = j >> 6, nz = j & 63;
        int kz = kcol >> 1;
        float a = (float)((kz * nz) & 63) * th;
        float val = (kcol & 1) ? -sinf(a) : cosf(a);
        TfT[j] = f2bf(val);
    } else if (idx < 9728) {
        int j = idx - 9216;                   // ny*8 + ky
        int ny = j >> 3, ky = j & 7;
        float a = (float)((ky * ny) & 63) * th;
        Tp1g[j * 2] = cosf(a);
        Tp1g[j * 2 + 1] = sinf(a);
    }
}

// XCD swizzle for 8192-block grids
__device__ __forceinline__ void swz8k(int blk, int& b, int& nx, int& ny) {
    int x = blk & 7;
    int j = blk >> 3;
    int pair = x * 16 + (j >> 6);
    ny = j & 63;
    b = pair >> 6;
    nx = pair & 63;
}

// x tile layout: [b][nxy][nz][pos] bf16, pos = quad*8 + ot*4 + r  <->  c = ot*16 + quad*4 + r.
// Writer emits one uint4/lane (fully coalesced); reader takes two uint2/lane (covered lines).

// ------- k_lift: MFMA lift conv + emb + MFMA forward z-DFT. -------
__global__ __launch_bounds__(256) void k_lift(const float* __restrict__ state_in,
        const float* __restrict__ node_pos, const unsigned short* __restrict__ wlbf,
        const float* __restrict__ embk, const unsigned short* __restrict__ TfT,
        unsigned short* __restrict__ x0, unsigned int* __restrict__ a1) {
    __shared__ __align__(16) float SL[3456];
    unsigned short* fsT  = (unsigned short*)SL;          // [nz][72] u16 (2304 f)
    unsigned short* ysbf = (unsigned short*)(SL + 2304); // [o][72] u16 (1152 f)
    int t = threadIdx.x;
    int b, nx, ny; swz8k(blockIdx.x, b, nx, ny);
    int nxy = nx * 64 + ny;

    {
        for (int u = t; u < 2048; u += 256) {
            int row = u >> 5, col = 37 + (u & 31);
            fsT[row * 72 + col] = 0;
        }
    }
    if (t < 192) {
        int nzf = t / 3;
        int l = t - nzf * 3;
        float p = node_pos[((size_t)b * 262144 + (nxy << 6)) * 3 + t];
        float s, c; sincosf(PI_F * p, &s, &c);
        unsigned short* row = fsT + nzf * 72;
        #pragma unroll
        for (int i = 0; i < 5; i++) {
            row[4 + l * 10 + i] = f2bf(c);
            row[4 + l * 10 + 5 + i] = f2bf(s);
            float nc = 2.0f * c * c - 1.0f;
            s = 2.0f * s * c;
            c = nc;
        }
        row[34 + l] = f2bf(p);
    } else {
        int nzf = t - 192;
        const float4 s4 = *(const float4*)(state_in + ((size_t)b * 262144 + (nxy << 6) + nzf) * 4);
        unsigned short* row = fsT + nzf * 72;
        row[0] = f2bf(s4.x); row[1] = f2bf(s4.y);
        row[2] = f2bf(s4.z); row[3] = f2bf(s4.w);
    }
    __syncthreads();

    int lane = t & 63;
    int w = rfl(t >> 6);
    int l15 = lane & 15;
    int quad = lane >> 4;
    int nz = w * 16 + l15;
    size_t xbase = ((size_t)(b * 4096 + nxy)) * 2048;

    U8 b0, b1_;
    b0.q  = *(const uint4*)(fsT + nz * 72 + (quad << 3));
    b1_.q = *(const uint4*)(fsT + nz * 72 + 32 + (quad << 3));
    unsigned short hh[2][4];
    #pragma unroll
    for (int ot = 0; ot < 2; ot++) {
        U8 aA, aB;
        aA.q = *(const uint4*)(wlbf + ((ot * 16 + l15) << 6) + (quad << 3));
        aB.q = *(const uint4*)(wlbf + ((ot * 16 + l15) << 6) + 32 + (quad << 3));
        float4 cbv = *(const float4*)(embk + b * 32 + ot * 16 + quad * 4);  // L1 broadcast
        floatx4 cb = {cbv.x, cbv.y, cbv.z, cbv.w};
        floatx4 d = __builtin_amdgcn_mfma_f32_16x16x32_bf16(aA.v, b0.v, cb, 0, 0, 0);
        d = __builtin_amdgcn_mfma_f32_16x16x32_bf16(aB.v, b1_.v, d, 0, 0, 0);
        #pragma unroll
        for (int r = 0; r < 4; r++) {
            hh[ot][r] = f2bf(d[r]);
            ysbf[(ot * 16 + quad * 4 + r) * 72 + nz] = hh[ot][r];
        }
    }
    *(uint4*)(x0 + xbase + nz * 32 + (quad << 3)) = make_uint4(
        (unsigned)hh[0][0] | ((unsigned)hh[0][1] << 16),
        (unsigned)hh[0][2] | ((unsigned)hh[0][3] << 16),
        (unsigned)hh[1][0] | ((unsigned)hh[1][1] << 16),
        (unsigned)hh[1][2] | ((unsigned)hh[1][3] << 16));
    __syncthreads();

    if (w < 2) {   // forward z-DFT: chained K, one wave per o-tile
        int o = w * 16 + l15;
        U8 ay0, ay1, bt0, bt1;
        ay0.q = *(const uint4*)(ysbf + o * 72 + (quad << 3));
        ay1.q = *(const uint4*)(ysbf + o * 72 + 32 + (quad << 3));
        bt0.q = *(const uint4*)(TfT + (l15 << 6) + (quad << 3));
        bt1.q = *(const uint4*)(TfT + (l15 << 6) + 32 + (quad << 3));
        floatx4 z = {0.0f, 0.0f, 0.0f, 0.0f};
        z = __builtin_amdgcn_mfma_f32_16x16x32_bf16(ay0.v, bt0.v, z, 0, 0, 0);
        z = __builtin_amdgcn_mfma_f32_16x16x32_bf16(ay1.v, bt1.v, z, 0, 0, 0);
        float p0 = __shfl_xor(z[0], 1), p1 = __shfl_xor(z[1], 1);
        float p2 = __shfl_xor(z[2], 1), p3 = __shfl_xor(z[3], 1);
        if (!(lane & 1)) {
            unsigned int* a1p = a1 + ((size_t)(b * 4096 + nxy)) * 256;
            int kz = l15 >> 1;
            a1p[(w * 16 + quad * 4 + 0) * 8 + kz] = pack2(z[0], p0);
            a1p[(w * 16 + quad * 4 + 1) * 8 + kz] = pack2(z[1], p1);
            a1p[(w * 16 + quad * 4 + 2) * 8 + kz] = pack2(z[2], p2);
            a1p[(w * 16 + quad * 4 + 3) * 8 + kz] = pack2(z[3], p3);
        }
    }
}

// =================== spectral mid-section (2 kernels) ===================

// k_ps1: forward y-DFT over ny-QUARTERS. 512 blocks.
// writes a2p[qtr][b][kz][ky][nx][c] float2
__global__ __launch_bounds__(256) void k_ps1(const unsigned int* __restrict__ a1,
        const float2* __restrict__ Tp1g, float2* __restrict__ a2p) {
    int blk = blockIdx.x, t = threadIdx.x;
    int x = blk & 7, r = blk >> 3;
    int pair = x * 16 + (r & 15);         // b*64+nx
    int qtr = r >> 4;
    const unsigned int* src = a1 + ((size_t)(pair * 64 + qtr * 16)) * 256 + t;
    float accr[8], acci[8];
    #pragma unroll
    for (int k = 0; k < 8; k++) { accr[k] = 0.0f; acci[k] = 0.0f; }
    #pragma unroll 4
    for (int j = 0; j < 16; j++) {
        int ny = qtr * 16 + j;
        unsigned int pv = src[(size_t)j * 256];
        float vx = bf2f((unsigned short)(pv & 0xffffu));
        float vy = bf2f((unsigned short)(pv >> 16));
        const float2* tw = Tp1g + ny * 8;    // block-uniform -> s_load
        #pragma unroll
        for (int ky = 0; ky < 8; ky++) {
            float2 w2 = tw[ky];
            accr[ky] += vx * w2.x + vy * w2.y;   // e^{-i ky ny θ}
            acci[ky] += vy * w2.x - vx * w2.y;
        }
    }
    int b = pair >> 6, nx = pair & 63;
    int c = t >> 3, kz = t & 7;
    float2* dst = a2p + ((size_t)((qtr * 2 + b) * 8 + kz)) * 16384 + nx * 32 + c;
    #pragma unroll
    for (int ky = 0; ky < 8; ky++)
        dst[(size_t)ky * 2048] = make_float2(accr[ky], acci[ky]);
}

// k_ps2: quarter-sum + x-DFT + mode-mix + inverse-x, fused. 128 blocks = (b,kz,ky).
// DFT phases use exact LDS twiddle tables (no serial rotation recurrence -> full ILP).
// reads a2p + wT[mode][i][o]; writes b1[b][nx][kz*8+ky][o] float2
__global__ __launch_bounds__(256) void k_ps2(const float2* __restrict__ a2p,
        const float2* __restrict__ wTl, const float2* __restrict__ Tp1g,
        float2* __restrict__ b1) {
    __shared__ __align__(16) float2 MS[2048];   // [nx][c]
    __shared__ __align__(16) float2 TW[512];    // [n][k] twiddle (cos,sin of nkθ)
    __shared__ __align__(16) float2 XS[256];    // [i][kx]
    __shared__ __align__(16) float2 YS[288];    // [o][9] padded
    int t = threadIdx.x, blk = blockIdx.x;
    int b = blk >> 6, kz = (blk >> 3) & 7, ky = blk & 7;
    size_t sb = (size_t)b * 131072 + kz * 16384 + ky * 2048;
    for (int k = 0; k < 8; k++) {               // A: quarter-sum
        int e = k * 256 + t;
        float2 v0 = a2p[sb + e];
        float2 v1 = a2p[sb + 262144 + e];
        float2 v2 = a2p[sb + 524288 + e];
        float2 v3 = a2p[sb + 786432 + e];
        MS[e] = make_float2(v0.x + v1.x + v2.x + v3.x,
                            v0.y + v1.y + v2.y + v3.y);
    }
    TW[t] = Tp1g[t];
    TW[256 + t] = Tp1g[256 + t];
    __syncthreads();
    {   // B: x-DFT via table, thread (c = t>>3, kx = t&7); independent iters (ILP)
        int c = t >> 3, kx = t & 7;
        float xr = 0.0f, xi = 0.0f;
        #pragma unroll 8
        for (int nx = 0; nx < 64; nx++) {
            float2 v = MS[nx * 32 + c];
            float2 w2 = TW[nx * 8 + kx];
            xr += v.x * w2.x + v.y * w2.y;       // e^{-i kx nx θ}
            xi += v.y * w2.x - v.x * w2.y;
        }
        XS[c * 8 + kx] = make_float2(xr, xi);
    }
    __syncthreads();
    {   // C: mode mix, thread (kx = t>>5, o = t&31); wT coalesced o-inner
        int kx = t >> 5, o = t & 31;
        const float2* wp = wTl + ((size_t)(kz * 64 + ky * 8 + kx)) * 1024 + o;
        float yr = 0.0f, yi = 0.0f;
        #pragma unroll 8
        for (int i = 0; i < 32; i++) {
            float2 xv = XS[i * 8 + kx];
            float2 wv = wp[i * 32];
            yr += xv.x * wv.x - xv.y * wv.y;
            yi += xv.x * wv.y + xv.y * wv.x;
        }
        YS[o * 9 + kx] = make_float2(yr, yi);
    }
    __syncthreads();
    {   // D: inverse-x (e^{+i}) via table, thread (nx8 = t>>5, o = t&31)
        int nx8 = t >> 5, o = t & 31;
        for (int j = 0; j < 8; j++) {
            int nx = nx8 * 8 + j;
            float rr = 0.0f, ri = 0.0f;
            #pragma unroll
            for (int kx = 0; kx < 8; kx++) {
                float2 y = YS[o * 9 + kx];
                float2 w2 = TW[nx * 8 + kx];
                rr += y.x * w2.x - y.y * w2.y;
                ri += y.x * w2.y + y.y * w2.x;
            }
            b1[((size_t)(b * 64 + nx)) * 2048 + (kz * 8 + ky) * 32 + o]
                = make_float2(rr, ri);
        }
    }
}

// ------- k_fin: LDS-staged b1 tile + register inverse-y + chained MFMA + gelu.
//         LDS phase-aliased: ysbf/pr overlay the dead bstage region after the
//         inverse-y barrier -> 17.9 KB total, 9 blocks/CU.
//         + (l<3) chained-K MFMA fwd z-DFT OR (l==3) fused proj+residual -------
__global__ __launch_bounds__(256) void k_fin(
        const unsigned short* __restrict__ xin, const float2* __restrict__ b1,
        const unsigned short* __restrict__ wbh, const float* __restrict__ bb,
        const unsigned short* __restrict__ Tinv, const unsigned short* __restrict__ TfT,
        const float2* __restrict__ Tp1g, unsigned short* __restrict__ xout,
        unsigned int* __restrict__ a1, int do_z, int do_proj,
        const float* __restrict__ state_in, const float* __restrict__ p1w,
        const float* __restrict__ p1b, const float* __restrict__ p2w,
        const float* __restrict__ p2b, float* __restrict__ outp) {
    __shared__ __align__(16) float S[4480];
    float* bstage = S;                                    // f 0..4220 (phases 1-2 only)
    unsigned short* ysbf = (unsigned short*)S;            // [o][72] u16, f 0..1152 (phase 3+)
    float* pr = S + 1152;                                 // f 1152..2176 (proj, phase 4+)
    unsigned int* msu = (unsigned int*)(S + 4224);        // [32 o][8 kz] uint, f 4224..4480
    int t = threadIdx.x;
    int b, nx, ny; swz8k(blockIdx.x, b, nx, ny);
    int nxy = nx * 64 + ny;
    int lane = t & 63;
    int w = rfl(t >> 6);
    int l15 = lane & 15;
    int quad = lane >> 4;
    int nz = w * 16 + l15;
    size_t xbase = ((size_t)(b * 4096 + nxy)) * 2048;

    // early fragment loads: latency hides under staging + inverse-y
    int posA = ((quad & 1) << 4) | ((quad >> 1) << 2);
    uint2 xlo = *(const uint2*)(xin + xbase + nz * 32 + posA);
    uint2 xhi = *(const uint2*)(xin + xbase + nz * 32 + posA + 8);
    U8 bx, btv, aw0, aw1;
    ((uint2*)&bx)[0] = xlo; ((uint2*)&bx)[1] = xhi;
    btv.q = *(const uint4*)(Tinv + (nz << 5) + (quad << 3));        // L1-broadcast
    aw0.q = *(const uint4*)(wbh + (l15 << 5) + (quad << 3));
    aw1.q = *(const uint4*)(wbh + ((16 + l15) << 5) + (quad << 3));
    float4 c0 = *(const float4*)(bb + quad * 4);                    // L1-broadcast bias
    float4 c1 = *(const float4*)(bb + 16 + quad * 4);
    floatx4 cb0 = {c0.x, c0.y, c0.z, c0.w};
    floatx4 cb1 = {c1.x, c1.y, c1.z, c1.w};

    // phase 1: stage b1 tile (16 KB) -> LDS, fully lane-coalesced (1 KB/instr/wave).
    // LDS pad: f2-slot s lives at byte s*8 + (s>>6)*16 (floor bank cost both sides).
    {
        const float4* b1g = (const float4*)(b1 + ((size_t)(b * 64 + nx)) * 2048);
        #pragma unroll
        for (int j = 0; j < 4; j++) {
            int p = j * 256 + t;              // f2-pair index, covers 0..1023
            float4 v = b1g[p];
            int s = p * 2;
            *(float4*)((char*)bstage + s * 8 + ((s >> 6) << 4)) = v;
        }
    }
    __syncthreads();

    {   // phase 2: inverse-y from staged LDS; thread (o = t>>3, kz = t&7); writes msu
        int o_ = t >> 3, kz_ = t & 7;
        const float2* tw = Tp1g + ny * 8;          // block-uniform -> s_load
        float mr = 0.0f, mi = 0.0f;
        #pragma unroll
        for (int ky = 0; ky < 8; ky++) {
            int g = kz_ * 256 + ky * 32 + o_;
            float2 v = *(const float2*)((char*)bstage + g * 8 + ((g >> 6) << 4));
            float2 w2 = tw[ky];
            mr += v.x * w2.x - v.y * w2.y;         // e^{+i ky ny θ}
            mi += v.x * w2.y + v.y * w2.x;
        }
        msu[o_ * 8 + kz_] = pack2(mr, -mi);
    }
    __syncthreads();   // bstage dead from here; ysbf/pr may overlay it

    // ---- phase 3: chained MFMA, both o-tiles in one wave (wave = nz-tile):
    //      D = bias + W·X (bypass) + M·Tinv (inverse-z, scale folded in Tinv) ----
    U8 am0, am1;
    if (quad < 2) {   // M fragment: K-cols 0..15 real, 16..31 zero (Tinv rows 8..15 = 0 too)
        am0.q = *(const uint4*)(msu + l15 * 8 + quad * 4);
        am1.q = *(const uint4*)(msu + (16 + l15) * 8 + quad * 4);
    } else {
        am0.q = make_uint4(0, 0, 0, 0);
        am1.q = make_uint4(0, 0, 0, 0);
    }
    floatx4 d0 = __builtin_amdgcn_mfma_f32_16x16x32_bf16(aw0.v, bx.v, cb0, 0, 0, 0);
    d0 = __builtin_amdgcn_mfma_f32_16x16x32_bf16(am0.v, btv.v, d0, 0, 0, 0);
    floatx4 d1 = __builtin_amdgcn_mfma_f32_16x16x32_bf16(aw1.v, bx.v, cb1, 0, 0, 0);
    d1 = __builtin_amdgcn_mfma_f32_16x16x32_bf16(am1.v, btv.v, d1, 0, 0, 0);

    unsigned short h0[4], h1[4];
    #pragma unroll
    for (int r = 0; r < 4; r++) {
        h0[r] = f2bf(gelu_sig(d0[r]));
        ysbf[(quad * 4 + r) * 72 + nz] = h0[r];
        h1[r] = f2bf(gelu_sig(d1[r]));
        ysbf[(16 + quad * 4 + r) * 72 + nz] = h1[r];
    }
    if (!do_proj) {   // one clean uint4/lane: wave covers 1 KB contiguous
        *(uint4*)(xout + xbase + nz * 32 + (quad << 3)) = make_uint4(
            (unsigned)h0[0] | ((unsigned)h0[1] << 16),
            (unsigned)h0[2] | ((unsigned)h0[3] << 16),
            (unsigned)h1[0] | ((unsigned)h1[1] << 16),
            (unsigned)h1[2] | ((unsigned)h1[3] << 16));
    }
    __syncthreads();

    if (do_z && w < 2) {   // phase 4a: forward z-DFT, chained K, one wave per o-tile
        int o = w * 16 + l15;
        U8 ay0, ay1, bt0, bt1;
        ay0.q = *(const uint4*)(ysbf + o * 72 + (quad << 3));
        ay1.q = *(const uint4*)(ysbf + o * 72 + 32 + (quad << 3));
        bt0.q = *(const uint4*)(TfT + (l15 << 6) + (quad << 3));
        bt1.q = *(const uint4*)(TfT + (l15 << 6) + 32 + (quad << 3));
        floatx4 z = {0.0f, 0.0f, 0.0f, 0.0f};
        z = __builtin_amdgcn_mfma_f32_16x16x32_bf16(ay0.v, bt0.v, z, 0, 0, 0);
        z = __builtin_amdgcn_mfma_f32_16x16x32_bf16(ay1.v, bt1.v, z, 0, 0, 0);
        float p0 = __shfl_xor(z[0], 1), p1 = __shfl_xor(z[1], 1);
        float p2 = __shfl_xor(z[2], 1), p3 = __shfl_xor(z[3], 1);
        if (!(lane & 1)) {
            unsigned int* a1p = a1 + ((size_t)(b * 4096 + nxy)) * 256;
            int kz = l15 >> 1;
            a1p[(w * 16 + quad * 4 + 0) * 8 + kz] = pack2(z[0], p0);
            a1p[(w * 16 + quad * 4 + 1) * 8 + kz] = pack2(z[1], p1);
            a1p[(w * 16 + quad * 4 + 2) * 8 + kz] = pack2(z[2], p2);
            a1p[(w * 16 + quad * 4 + 3) * 8 + kz] = pack2(z[3], p3);
        }
    }

    if (do_proj) {   // phase 4b: fused proj1 -> gelu -> proj2 -> residual
        int nzp = t & 63;
        float xv[32];
        #pragma unroll
        for (int i = 0; i < 32; i++) xv[i] = bf2f(ysbf[i * 72 + nzp]);
        float r0 = 0.f, r1 = 0.f, r2 = 0.f, r3 = 0.f;
        #pragma unroll
        for (int k = 0; k < 8; k++) {
            int o = w * 8 + k;
            float a = p1b[o];                                   // s_load
            const float* wr = p1w + o * 32;                     // s_load
            #pragma unroll
            for (int i = 0; i < 32; i++) a += wr[i] * xv[i];
            float h = gelu_sig(a);
            r0 += p2w[0 * 32 + o] * h;
            r1 += p2w[1 * 32 + o] * h;
            r2 += p2w[2 * 32 + o] * h;
            r3 += p2w[3 * 32 + o] * h;
        }
        *(float4*)(pr + w * 256 + nzp * 4) = make_float4(r0, r1, r2, r3);
        __syncthreads();
        if (t < 64) {
            float4 a0 = *(float4*)(pr + 0 * 256 + t * 4);
            float4 a1_ = *(float4*)(pr + 1 * 256 + t * 4);
            float4 a2 = *(float4*)(pr + 2 * 256 + t * 4);
            float4 a3 = *(float4*)(pr + 3 * 256 + t * 4);
            size_t base = ((size_t)b * 262144 + (nxy << 6) + t) * 4;
            float4 sv = *(const float4*)(state_in + base);
            *(float4*)(outp + base) = make_float4(
                sv.x + 0.05f * (p2b[0] + a0.x + a1_.x + a2.x + a3.x),
                sv.y + 0.05f * (p2b[1] + a0.y + a1_.y + a2.y + a3.y),
                sv.z + 0.05f * (p2b[2] + a0.z + a1_.z + a2.z + a3.z),
                sv.w + 0.05f * (p2b[3] + a0.w + a1_.w + a2.w + a3.w));
        }
    }
}

extern "C" void kernel_launch(void* const* d_in, const int* in_sizes, int n_in,
                              void* d_out, int out_size, void* d_ws, size_t ws_size,
                              hipStream_t stream) {
    const float* state_in   = (const float*)d_in[0];
    const float* node_pos   = (const float*)d_in[1];
    const float* time_i     = (const float*)d_in[3];
    const float* conditions = (const float*)d_in[4];
    const float* t_embed_w  = (const float*)d_in[5];
    const float* t_embed_b  = (const float*)d_in[6];
    const float* c_embed_w  = (const float*)d_in[7];
    const float* c_embed_b  = (const float*)d_in[8];
    const float* lift_w     = (const float*)d_in[9];
    const float* lift_b     = (const float*)d_in[10];
    const float* spec_wr    = (const float*)d_in[11];
    const float* spec_wi    = (const float*)d_in[12];
    const float* byp_w      = (const float*)d_in[13];
    const float* byp_b      = (const float*)d_in[14];
    const float* proj1_w    = (const float*)d_in[15];
    const float* proj1_b    = (const float*)d_in[16];
    const float* proj2_w    = (const float*)d_in[17];
    const float* proj2_b    = (const float*)d_in[18];
    float* out = (float*)d_out;
    float* ws  = (float*)d_ws;

    unsigned short* xA = (unsigned short*)ws;                 // 16777216 u16
    unsigned short* xB = (unsigned short*)(ws + 8388608);     // 16777216 u16
    unsigned int* a1 = (unsigned int*)(ws + 16777216);        // 1048576 uint (bf16x2)
    float2* a2p  = (float2*)(ws + 20971520);   // 1048576 f2 -> 23068672
    float2* b1   = (float2*)(ws + 23396352);   // 262144 f2  -> 23920640
    float*  embk = ws + 23920640;              // 64
    unsigned short* wbh  = (unsigned short*)(ws + 23920704);  // 4096 u16 -> 23922752
    unsigned short* wlbf = (unsigned short*)(ws + 23922752);  // 2048 u16 -> 23923776
    unsigned short* Tinv = (unsigned short*)(ws + 23923776);  // 2048 u16 -> 23924800
    unsigned short* TfT  = (unsigned short*)(ws + 23924800);  // 1024 u16 -> 23925312
    float* Tp1gf = ws + 23925312;              // 1024 f (512 float2)
    float2* Tp1g = (float2*)Tp1gf;
    float2* wT   = (float2*)(ws + 23926336);   // 2097152 f2 (16 MB) -> 28120640

    k_wt<<<552, 256, 0, stream>>>(time_i, conditions, t_embed_w, t_embed_b,
                                  c_embed_w, c_embed_b, lift_b, embk,
                                  byp_w, lift_w, wbh, wlbf, Tinv, TfT, Tp1gf,
                                  spec_wr, spec_wi, wT);
    k_lift<<<8192, 256, 0, stream>>>(state_in, node_pos, wlbf, embk, TfT, xA, a1);

    for (int l = 0; l < 4; l++) {
        unsigned short* xin  = (l & 1) ? xB : xA;
        unsigned short* xout = (l & 1) ? xA : xB;
        k_ps1<<<512, 256, 0, stream>>>(a1, Tp1g, a2p);
        k_ps2<<<128, 256, 0, stream>>>(a2p, wT + (size_t)l * 524288, Tp1g, b1);
        k_fin<<<8192, 256, 0, stream>>>(xin, b1, wbh + l * 1024, byp_b + l * 32,
                                        Tinv, TfT, Tp1g, xout, a1, (l < 3) ? 1 : 0,
                                        (l == 3) ? 1 : 0, state_in,
                                        proj1_w, proj1_b, proj2_w, proj2_b, out);
    }
}